// Round 6
// baseline (117.779 us; speedup 1.0000x reference)
//
#include <hip/hip_runtime.h>

// Problem constants (from setup_inputs): disp [8,384,1280,1] f32
#define BATCH 8
#define HH 384
#define WW 1280
#define TW 32           // tile width  (threads x)
#define TH 16           // tile height (threads y)  [R6: 8 -> 16]
#define NT (TW * TH)    // 512 threads
#define LW (TW + 4)     // 36: tile + 2-halo each side
#define LH (TH + 4)     // 20

// Fast-math helpers (mask-path only; depth output keeps IEEE div).
__device__ __forceinline__ float fast_rcp(float x) {
  float r = __builtin_amdgcn_rcpf(x);
  return fmaf(r, fmaf(-x, r, 1.0f), r);  // 1 Newton step, ~0.5 ulp
}
__device__ __forceinline__ float fast_sqrt(float x) {
  return __builtin_amdgcn_sqrtf(x);      // v_sqrt_f32, ~1 ulp
}
__device__ __forceinline__ float cos_rev(float r) {  // cos(2*pi*r)
  float d;
  asm("v_cos_f32 %0, %1" : "=v"(d) : "v"(r));
  return d;
}

// ---------------------------------------------------------------------------
// Per-batch prep: K1 = K_scale @ K0, K1^{-1} (double adjugate), fxb = K1[0,0]*b
// ---------------------------------------------------------------------------
__global__ void prep_kernel(const float* __restrict__ K0,
                            const float* __restrict__ baseline,
                            const int* __restrict__ h0p,
                            const int* __restrict__ w0p,
                            float* __restrict__ cst) {
  int b = threadIdx.x;
  if (b >= BATCH) return;
  float w0 = (float)w0p[0];
  float h0 = (float)h0p[0];
  float rw = (float)WW / w0;
  float rh = (float)HH / h0;
  float s02 = 0.5f * (rw - 1.0f);
  float s12 = 0.5f * (rh - 1.0f);
  const float* K = K0 + b * 9;
  float k0 = rw * K[0] + s02 * K[6];
  float k1 = rw * K[1] + s02 * K[7];
  float k2 = rw * K[2] + s02 * K[8];
  float k3 = rh * K[3] + s12 * K[6];
  float k4 = rh * K[4] + s12 * K[7];
  float k5 = rh * K[5] + s12 * K[8];
  float k6 = K[6], k7 = K[7], k8 = K[8];
  double a = k0, bb = k1, c = k2, d = k3, e = k4, f = k5, g = k6, h = k7, i = k8;
  double cA = e * i - f * h;
  double cB = -(d * i - f * g);
  double cC = d * h - e * g;
  double det = a * cA + bb * cB + c * cC;
  double idet = 1.0 / det;
  float* o = cst + b * 12;
  o[0] = (float)(cA * idet);
  o[1] = (float)(-(bb * i - c * h) * idet);
  o[2] = (float)((bb * f - c * e) * idet);
  o[3] = (float)(cB * idet);
  o[4] = (float)((a * i - c * g) * idet);
  o[5] = (float)(-(a * f - c * d) * idet);
  o[6] = (float)(cC * idet);
  o[7] = (float)(-(a * h - bb * g) * idet);
  o[8] = (float)((a * e - bb * d) * idet);
  o[9] = k0 * baseline[b];
}

// ---------------------------------------------------------------------------
// Fused kernel, separable 5x5 window, 32x16 tile (512 threads):
//   stage 1: xyz(+depth) tile in LDS (zero-pad outside image)
//   stage 2: vertical 5-sums of the 9 moment channels -> LDS
//   stage 3: horizontal 5-sums + eigen epilogue (HW trans, rcp+NR divides)
// LDS: 11.5K + 9.2K + 9.2K + 2.3K = 32.3 KB -> 4 blocks/CU = 32 waves (cap)
// ---------------------------------------------------------------------------
__global__ __launch_bounds__(512) void tmap_fused(
    const float* __restrict__ disp,
    const float* __restrict__ cst,
    float* __restrict__ out_depth,
    float* __restrict__ out_mask) {
  __shared__ float4 tile[LH][LW];   // x, y, z, depth
  __shared__ float4 vs0[TH][LW];    // sx, sy, sz, sxx
  __shared__ float4 vs1[TH][LW];    // sxy, sxz, syy, syz
  __shared__ float  vs2[TH][LW];    // szz

  const int b = blockIdx.z;
  const float* C = cst + b * 12;
  const float Ki00 = C[0], Ki01 = C[1], Ki02 = C[2];
  const float Ki10 = C[3], Ki11 = C[4], Ki12 = C[5];
  const float Ki20 = C[6], Ki21 = C[7], Ki22 = C[8];
  const float fxb = C[9];

  const int j0 = blockIdx.x * TW;
  const int i0 = blockIdx.y * TH;
  const int tid = threadIdx.y * TW + threadIdx.x;

  // ---- stage 1: xyz(+depth) for tile + halo; zero outside image
  for (int s = tid; s < LH * LW; s += NT) {
    const int ti = s / LW;
    const int tj = s - ti * LW;
    const int gi = i0 - 2 + ti;
    const int gj = j0 - 2 + tj;
    float4 v = make_float4(0.0f, 0.0f, 0.0f, 0.0f);
    if (gi >= 0 && gi < HH && gj >= 0 && gj < WW) {
      const float dsp = disp[(b * HH + gi) * WW + gj];
      const float dd = (float)WW * fmaxf(dsp, 1e-6f);
      const float depth = fxb / dd;           // IEEE: feeds depth output
      const float jf = (float)gj;
      const float iff = (float)gi;
      v.x = depth * fmaf(Ki00, jf, fmaf(Ki01, iff, Ki02));
      v.y = depth * fmaf(Ki10, jf, fmaf(Ki11, iff, Ki12));
      v.z = depth * fmaf(Ki20, jf, fmaf(Ki21, iff, Ki22));
      v.w = depth;
    }
    tile[ti][tj] = v;
  }
  __syncthreads();

  // ---- stage 2: vertical 5-sums at TH x LW positions
  for (int s = tid; s < TH * LW; s += NT) {
    const int ti = s / LW;
    const int tj = s - ti * LW;
    float sx = 0.f, sy = 0.f, sz = 0.f;
    float sxx = 0.f, sxy = 0.f, sxz = 0.f, syy = 0.f, syz = 0.f, szz = 0.f;
#pragma unroll
    for (int k = 0; k < 5; ++k) {
      const float4 v = tile[ti + k][tj];
      sx += v.x; sy += v.y; sz += v.z;
      sxx = fmaf(v.x, v.x, sxx);
      sxy = fmaf(v.x, v.y, sxy);
      sxz = fmaf(v.x, v.z, sxz);
      syy = fmaf(v.y, v.y, syy);
      syz = fmaf(v.y, v.z, syz);
      szz = fmaf(v.z, v.z, szz);
    }
    vs0[ti][tj] = make_float4(sx, sy, sz, sxx);
    vs1[ti][tj] = make_float4(sxy, sxz, syy, syz);
    vs2[ti][tj] = szz;
  }
  __syncthreads();

  // ---- stage 3: horizontal 5-sums
  float s1x = 0.f, s1y = 0.f, s1z = 0.f;
  float m00 = 0.f, m01 = 0.f, m02 = 0.f, m11 = 0.f, m12 = 0.f, m22 = 0.f;
#pragma unroll
  for (int w = 0; w < 5; ++w) {
    const float4 va = vs0[threadIdx.y][threadIdx.x + w];
    const float4 vb = vs1[threadIdx.y][threadIdx.x + w];
    const float vc = vs2[threadIdx.y][threadIdx.x + w];
    s1x += va.x; s1y += va.y; s1z += va.z; m00 += va.w;
    m01 += vb.x; m02 += vb.y; m11 += vb.z; m12 += vb.w;
    m22 += vc;
  }

  const int gi = i0 + threadIdx.y;
  const int gj = j0 + threadIdx.x;
  const int ch = min(gi + 2, HH - 1) - max(gi - 2, 0) + 1;
  const int cw = min(gj + 2, WW - 1) - max(gj - 2, 0) + 1;
  const float cnt = (float)(ch * cw);
  const float rcnt = fast_rcp(cnt);

  const float Px = s1x * rcnt, Py = s1y * rcnt, Pz = s1z * rcnt;
  float a00 = m00 * rcnt - Px * Px;
  float a01 = m01 * rcnt - Px * Py;
  float a02 = m02 * rcnt - Px * Pz;
  float a11 = m11 * rcnt - Py * Py;
  float a12 = m12 * rcnt - Py * Pz;
  float a22 = m22 * rcnt - Pz * Pz;

  float Amax = fmaxf(fabsf(a00), fabsf(a11));
  Amax = fmaxf(Amax, fabsf(a22));
  Amax = fmaxf(Amax, fabsf(a01));
  Amax = fmaxf(Amax, fabsf(a02));
  Amax = fmaxf(Amax, fabsf(a12));
  const float eval_zero = (Amax < 1e-6f) ? 1.0f : 0.0f;
  const float rAm = fast_rcp(fmaxf(Amax, 1e-6f));
  a00 *= rAm; a01 *= rAm; a02 *= rAm; a11 *= rAm; a12 *= rAm; a22 *= rAm;

  const float nrm = a01 * a01 + a02 * a02 + a12 * a12;
  const float q = (a00 + a11 + a22) * (1.0f / 3.0f);
  const float b00 = a00 - q, b11 = a11 - q, b22 = a22 - q;
  const float p =
      fast_sqrt((b00 * b00 + b11 * b11 + b22 * b22 + 2.0f * nrm) * (1.0f / 6.0f));
  const float eig_triple = ((p < 1e-6f) ? 1.0f : 0.0f) * (1.0f - eval_zero);
  const float c00 = b11 * b22 - a12 * a12;
  const float c01 = a01 * b22 - a12 * a02;
  const float c02 = a01 * a12 - b11 * a02;
  const float rpm = fast_rcp(fmaxf(p, 1e-6f));
  const float det = (b00 * c00 - a01 * c01 + a02 * c02) * (rpm * rpm * rpm);
  const float half_det = fminf(fmaxf(0.5f * det, -1.0f), 1.0f);
  // angle = acos(half_det)/3; betas via HW v_cos (input in revolutions)
  const float t = acosf(half_det);
  const float rev = t * 0.05305164769729845f;  // 1/(6*pi)
  const float beta2 = 2.0f * cos_rev(rev);                    // 2*cos(t/3)
  const float beta0 = 2.0f * cos_rev(rev + (1.0f / 3.0f));    // 2*cos(t/3+2pi/3)
  const float beta1 = -(beta0 + beta2);
  float e0 = q + p * beta0;
  float e1 = q + p * beta1;
  float e2 = q + p * beta2;
  const float wsel = (1.0f - eval_zero) * (1.0f - eig_triple);
  e0 = eig_triple * q + wsel * e0;
  e1 = eig_triple * q + wsel * e1;
  e2 = eig_triple * q + wsel * e2;

  const float denom = fast_sqrt(fmaxf((e0 - e1) * (e0 - e2), 0.0f));
  const float evec_zero = (denom < 1e-6f) ? 1.0f : 0.0f;
  const float ny_num =
      fast_sqrt(fmaxf(e0 * e0 - (a00 + a22) * e0 + (a00 * a22 - a02 * a02), 0.0f));
  const float ny =
      fminf(fmaxf(ny_num * fast_rcp(fmaxf(denom, 1e-6f)), 0.0f), 1.0f);
  const float plane_xz = (1.0f - evec_zero) * ny;

  const float4 ctr = tile[threadIdx.y + 2][threadIdx.x + 2];
  const float cond1 = (ctr.y > 0.3f) ? 1.0f : 0.0f;
  const float cond2 = (plane_xz > 0.85f) ? 1.0f : 0.0f;

  const int idx = (b * HH + gi) * WW + gj;
  out_depth[idx] = ctr.w;
  out_mask[idx] = cond1 * cond2;
}

extern "C" void kernel_launch(void* const* d_in, const int* in_sizes, int n_in,
                              void* d_out, int out_size, void* d_ws, size_t ws_size,
                              hipStream_t stream) {
  const float* disp = (const float*)d_in[0];
  const float* K0 = (const float*)d_in[1];
  const float* baseline = (const float*)d_in[2];
  const int* h0 = (const int*)d_in[3];
  const int* w0 = (const int*)d_in[4];

  float* cst = (float*)d_ws;  // 8 * 12 floats = 384 B
  float* out_depth = (float*)d_out;
  float* out_mask = out_depth + (size_t)BATCH * HH * WW;

  prep_kernel<<<1, BATCH, 0, stream>>>(K0, baseline, h0, w0, cst);

  dim3 block(TW, TH);
  dim3 grid(WW / TW, HH / TH, BATCH);
  tmap_fused<<<grid, block, 0, stream>>>(disp, cst, out_depth, out_mask);
}

// Round 9
// 116.863 us; speedup vs baseline: 1.0078x; 1.0078x over previous
//
#include <hip/hip_runtime.h>

// Problem constants (from setup_inputs): disp [8,384,1280,1] f32
#define BATCH 8
#define HH 384
#define WW 1280
#define TW 32           // tile width  (threads x)
#define TH 8            // tile height (threads y)  [R7: revert to 8 — R6's 16 regressed]
#define NT (TW * TH)    // 256 threads
#define LW (TW + 4)     // 36: tile + 2-halo each side
#define LH (TH + 4)     // 12

// Fast-math helpers (mask-path + depth; ~1 ulp, tolerance-validated R5).
__device__ __forceinline__ float fast_rcp(float x) {
  float r = __builtin_amdgcn_rcpf(x);
  return fmaf(r, fmaf(-x, r, 1.0f), r);  // 1 Newton step, ~0.5 ulp
}
__device__ __forceinline__ float fast_sqrt(float x) {
  return __builtin_amdgcn_sqrtf(x);      // v_sqrt_f32, ~1 ulp
}
__device__ __forceinline__ float cos_rev(float r) {  // cos(2*pi*r)
  float d;
  asm("v_cos_f32 %0, %1" : "=v"(d) : "v"(r));
  return d;
}
// acos via asin reduction (cephes asinf poly), rel err ~1e-7, ~14 inst.
__device__ __forceinline__ float fast_acos(float x) {
  const float ax = fabsf(x);
  const bool big = ax > 0.5f;
  const float z = big ? (1.0f - ax) * 0.5f : x * x;
  const float u = big ? fast_sqrt(z) : x;    // signed in small path
  float pz = fmaf(z, 4.2163199048e-2f, 2.4181311049e-2f);
  pz = fmaf(z, pz, 4.5470025998e-2f);
  pz = fmaf(z, pz, 7.4953002686e-2f);
  pz = fmaf(z, pz, 1.6666752422e-1f);
  const float r = fmaf(u * z, pz, u);        // asin(u)
  const float big_res = (x < 0.0f) ? fmaf(-2.0f, r, 3.14159265358979f) : 2.0f * r;
  const float small_res = 1.57079632679490f - r;
  return big ? big_res : small_res;
}

// ---------------------------------------------------------------------------
// Per-batch prep: K1 = K_scale @ K0, K1^{-1} (double adjugate), fxb = K1[0,0]*b
// ---------------------------------------------------------------------------
__global__ void prep_kernel(const float* __restrict__ K0,
                            const float* __restrict__ baseline,
                            const int* __restrict__ h0p,
                            const int* __restrict__ w0p,
                            float* __restrict__ cst) {
  int b = threadIdx.x;
  if (b >= BATCH) return;
  float w0 = (float)w0p[0];
  float h0 = (float)h0p[0];
  float rw = (float)WW / w0;
  float rh = (float)HH / h0;
  float s02 = 0.5f * (rw - 1.0f);
  float s12 = 0.5f * (rh - 1.0f);
  const float* K = K0 + b * 9;
  float k0 = rw * K[0] + s02 * K[6];
  float k1 = rw * K[1] + s02 * K[7];
  float k2 = rw * K[2] + s02 * K[8];
  float k3 = rh * K[3] + s12 * K[6];
  float k4 = rh * K[4] + s12 * K[7];
  float k5 = rh * K[5] + s12 * K[8];
  float k6 = K[6], k7 = K[7], k8 = K[8];
  double a = k0, bb = k1, c = k2, d = k3, e = k4, f = k5, g = k6, h = k7, i = k8;
  double cA = e * i - f * h;
  double cB = -(d * i - f * g);
  double cC = d * h - e * g;
  double det = a * cA + bb * cB + c * cC;
  double idet = 1.0 / det;
  float* o = cst + b * 12;
  o[0] = (float)(cA * idet);
  o[1] = (float)(-(bb * i - c * h) * idet);
  o[2] = (float)((bb * f - c * e) * idet);
  o[3] = (float)(cB * idet);
  o[4] = (float)((a * i - c * g) * idet);
  o[5] = (float)(-(a * f - c * d) * idet);
  o[6] = (float)(cC * idet);
  o[7] = (float)(-(a * h - bb * g) * idet);
  o[8] = (float)((a * e - bb * d) * idet);
  o[9] = k0 * baseline[b];
}

// ---------------------------------------------------------------------------
// Fused kernel, separable 5x5 window, 32x8 tile (256 threads):
//   stage 1: xyz(+depth) tile in LDS (zero-pad outside image)
//   stage 2: vertical 5-sums of the 9 moment channels -> LDS
//   stage 3: horizontal 5-sums + slim eigen epilogue
// LDS 17.4 KB -> 8 blocks/CU (32-wave cap)
// ---------------------------------------------------------------------------
__global__ __launch_bounds__(256) void tmap_fused(
    const float* __restrict__ disp,
    const float* __restrict__ cst,
    float* __restrict__ out_depth,
    float* __restrict__ out_mask) {
  __shared__ float4 tile[LH][LW];   // x, y, z, depth
  __shared__ float4 vs0[TH][LW];    // sx, sy, sz, sxx
  __shared__ float4 vs1[TH][LW];    // sxy, sxz, syy, syz
  __shared__ float  vs2[TH][LW];    // szz

  const int b = blockIdx.z;
  const float* C = cst + b * 12;
  const float Ki00 = C[0], Ki01 = C[1], Ki02 = C[2];
  const float Ki10 = C[3], Ki11 = C[4], Ki12 = C[5];
  const float Ki20 = C[6], Ki21 = C[7], Ki22 = C[8];
  const float fxb = C[9];

  const int j0 = blockIdx.x * TW;
  const int i0 = blockIdx.y * TH;
  const int tid = threadIdx.y * TW + threadIdx.x;

  // ---- stage 1: xyz(+depth) for tile + halo; zero outside image
  for (int s = tid; s < LH * LW; s += NT) {
    const int ti = s / LW;
    const int tj = s - ti * LW;
    const int gi = i0 - 2 + ti;
    const int gj = j0 - 2 + tj;
    float4 v = make_float4(0.0f, 0.0f, 0.0f, 0.0f);
    if (gi >= 0 && gi < HH && gj >= 0 && gj < WW) {
      const float dsp = disp[(b * HH + gi) * WW + gj];
      const float dd = (float)WW * fmaxf(dsp, 1e-6f);
      const float depth = fxb * fast_rcp(dd);   // ~1 ulp vs IEEE div
      const float jf = (float)gj;
      const float iff = (float)gi;
      v.x = depth * fmaf(Ki00, jf, fmaf(Ki01, iff, Ki02));
      v.y = depth * fmaf(Ki10, jf, fmaf(Ki11, iff, Ki12));
      v.z = depth * fmaf(Ki20, jf, fmaf(Ki21, iff, Ki22));
      v.w = depth;
    }
    tile[ti][tj] = v;
  }
  __syncthreads();

  // ---- stage 2: vertical 5-sums at TH x LW positions
  for (int s = tid; s < TH * LW; s += NT) {
    const int ti = s / LW;
    const int tj = s - ti * LW;
    float sx = 0.f, sy = 0.f, sz = 0.f;
    float sxx = 0.f, sxy = 0.f, sxz = 0.f, syy = 0.f, syz = 0.f, szz = 0.f;
#pragma unroll
    for (int k = 0; k < 5; ++k) {
      const float4 v = tile[ti + k][tj];
      sx += v.x; sy += v.y; sz += v.z;
      sxx = fmaf(v.x, v.x, sxx);
      sxy = fmaf(v.x, v.y, sxy);
      sxz = fmaf(v.x, v.z, sxz);
      syy = fmaf(v.y, v.y, syy);
      syz = fmaf(v.y, v.z, syz);
      szz = fmaf(v.z, v.z, szz);
    }
    vs0[ti][tj] = make_float4(sx, sy, sz, sxx);
    vs1[ti][tj] = make_float4(sxy, sxz, syy, syz);
    vs2[ti][tj] = szz;
  }
  __syncthreads();

  // ---- stage 3: horizontal 5-sums
  float s1x = 0.f, s1y = 0.f, s1z = 0.f;
  float m00 = 0.f, m01 = 0.f, m02 = 0.f, m11 = 0.f, m12 = 0.f, m22 = 0.f;
#pragma unroll
  for (int w = 0; w < 5; ++w) {
    const float4 va = vs0[threadIdx.y][threadIdx.x + w];
    const float4 vb = vs1[threadIdx.y][threadIdx.x + w];
    const float vc = vs2[threadIdx.y][threadIdx.x + w];
    s1x += va.x; s1y += va.y; s1z += va.z; m00 += va.w;
    m01 += vb.x; m02 += vb.y; m11 += vb.z; m12 += vb.w;
    m22 += vc;
  }

  const int gi = i0 + threadIdx.y;
  const int gj = j0 + threadIdx.x;
  const int ch = min(gi + 2, HH - 1) - max(gi - 2, 0) + 1;
  const int cw = min(gj + 2, WW - 1) - max(gj - 2, 0) + 1;
  const float cnt = (float)(ch * cw);
  const float rcnt = fast_rcp(cnt);

  const float Px = s1x * rcnt, Py = s1y * rcnt, Pz = s1z * rcnt;
  float a00 = m00 * rcnt - Px * Px;
  float a01 = m01 * rcnt - Px * Py;
  float a02 = m02 * rcnt - Px * Pz;
  float a11 = m11 * rcnt - Py * Py;
  float a12 = m12 * rcnt - Py * Pz;
  float a22 = m22 * rcnt - Pz * Pz;

  const float AmA = fmaxf(fmaxf(fabsf(a00), fabsf(a11)), fabsf(a22));
  const float AmB = fmaxf(fmaxf(fabsf(a01), fabsf(a02)), fabsf(a12));
  const float Amax = fmaxf(AmA, AmB);
  const float eval_zero = (Amax < 1e-6f) ? 1.0f : 0.0f;
  const float rAm = fast_rcp(fmaxf(Amax, 1e-6f));
  a00 *= rAm; a01 *= rAm; a02 *= rAm; a11 *= rAm; a12 *= rAm; a22 *= rAm;

  const float nrm = a01 * a01 + a02 * a02 + a12 * a12;
  const float q = (a00 + a11 + a22) * (1.0f / 3.0f);
  const float b00 = a00 - q, b11 = a11 - q, b22 = a22 - q;
  const float p =
      fast_sqrt((b00 * b00 + b11 * b11 + b22 * b22 + 2.0f * nrm) * (1.0f / 6.0f));
  const float eig_triple = ((p < 1e-6f) ? 1.0f : 0.0f) * (1.0f - eval_zero);
  const float c00 = b11 * b22 - a12 * a12;
  const float c01 = a01 * b22 - a12 * a02;
  const float c02 = a01 * a12 - b11 * a02;
  const float rpm = fast_rcp(fmaxf(p, 1e-6f));
  const float det = (b00 * c00 - a01 * c01 + a02 * c02) * (rpm * rpm * rpm);
  const float half_det = fminf(fmaxf(0.5f * det, -1.0f), 1.0f);
  // angle = acos(half_det)/3; betas via HW v_cos (input in revolutions)
  const float t = fast_acos(half_det);
  const float rev = t * 0.05305164769729845f;  // 1/(6*pi)
  const float beta2 = 2.0f * cos_rev(rev);                    // 2*cos(t/3)
  const float beta0 = 2.0f * cos_rev(rev + (1.0f / 3.0f));    // 2*cos(t/3+2pi/3)
  const float wsel = (1.0f - eval_zero) * (1.0f - eig_triple);
  // selected smallest eigenvalue
  const float e0 = eig_triple * q + wsel * fmaf(p, beta0, q);
  // denom = sqrt(max((e0-e1)(e0-e2),0)) with selected evals
  //       = wsel * p * sqrt(max((2*b0+b2)*(b0-b2), 0))   [b1 = -(b0+b2)]
  const float dd2 = (2.0f * beta0 + beta2) * (beta0 - beta2);
  const float denom = wsel * p * fast_sqrt(fmaxf(dd2, 0.0f));
  const float evec_zero = (denom < 1e-6f) ? 1.0f : 0.0f;
  const float ny_num =
      fast_sqrt(fmaxf(e0 * e0 - (a00 + a22) * e0 + (a00 * a22 - a02 * a02), 0.0f));
  const float ny =
      fminf(fmaxf(ny_num * fast_rcp(fmaxf(denom, 1e-6f)), 0.0f), 1.0f);
  const float plane_xz = (1.0f - evec_zero) * ny;

  const float4 ctr = tile[threadIdx.y + 2][threadIdx.x + 2];
  const float cond1 = (ctr.y > 0.3f) ? 1.0f : 0.0f;
  const float cond2 = (plane_xz > 0.85f) ? 1.0f : 0.0f;

  const int idx = (b * HH + gi) * WW + gj;
  out_depth[idx] = ctr.w;
  out_mask[idx] = cond1 * cond2;
}

extern "C" void kernel_launch(void* const* d_in, const int* in_sizes, int n_in,
                              void* d_out, int out_size, void* d_ws, size_t ws_size,
                              hipStream_t stream) {
  const float* disp = (const float*)d_in[0];
  const float* K0 = (const float*)d_in[1];
  const float* baseline = (const float*)d_in[2];
  const int* h0 = (const int*)d_in[3];
  const int* w0 = (const int*)d_in[4];

  float* cst = (float*)d_ws;  // 8 * 12 floats = 384 B
  float* out_depth = (float*)d_out;
  float* out_mask = out_depth + (size_t)BATCH * HH * WW;

  prep_kernel<<<1, BATCH, 0, stream>>>(K0, baseline, h0, w0, cst);

  dim3 block(TW, TH);
  dim3 grid(WW / TW, HH / TH, BATCH);
  tmap_fused<<<grid, block, 0, stream>>>(disp, cst, out_depth, out_mask);
}

// Round 12
// 111.314 us; speedup vs baseline: 1.0581x; 1.0498x over previous
//
#include <hip/hip_runtime.h>

// Problem constants (from setup_inputs): disp [8,384,1280,1] f32
#define BATCH 8
#define HH 384
#define WW 1280
#define OUTW 60          // output columns per wave (64 lanes - 4 halo)
#define CH 8             // output rows per wave
#define NSX 22           // ceil(1280/60)
#define NCY 48           // 384/8
// units = NSX*NCY*BATCH = 8448 waves = 2112 blocks of 4 waves

// Fast-math helpers (validated through R9: passed, absmax tolerance loose).
__device__ __forceinline__ float fast_rcp(float x) {
  float r = __builtin_amdgcn_rcpf(x);
  return fmaf(r, fmaf(-x, r, 1.0f), r);
}
__device__ __forceinline__ float fast_sqrt(float x) {
  return __builtin_amdgcn_sqrtf(x);
}
__device__ __forceinline__ float cos_rev(float r) {  // cos(2*pi*r)
  float d;
  asm("v_cos_f32 %0, %1" : "=v"(d) : "v"(r));
  return d;
}
__device__ __forceinline__ float fast_acos(float x) {
  const float ax = fabsf(x);
  const bool big = ax > 0.5f;
  const float z = big ? (1.0f - ax) * 0.5f : x * x;
  const float u = big ? fast_sqrt(z) : x;
  float pz = fmaf(z, 4.2163199048e-2f, 2.4181311049e-2f);
  pz = fmaf(z, pz, 4.5470025998e-2f);
  pz = fmaf(z, pz, 7.4953002686e-2f);
  pz = fmaf(z, pz, 1.6666752422e-1f);
  const float r = fmaf(u * z, pz, u);
  const float big_res = (x < 0.0f) ? fmaf(-2.0f, r, 3.14159265358979f) : 2.0f * r;
  const float small_res = 1.57079632679490f - r;
  return big ? big_res : small_res;
}

// ---------------------------------------------------------------------------
// Per-batch prep (unchanged, validated): K1, K1^{-1}, fxb -> cst[12] per batch
// ---------------------------------------------------------------------------
__global__ void prep_kernel(const float* __restrict__ K0,
                            const float* __restrict__ baseline,
                            const int* __restrict__ h0p,
                            const int* __restrict__ w0p,
                            float* __restrict__ cst) {
  int b = threadIdx.x;
  if (b >= BATCH) return;
  float w0 = (float)w0p[0];
  float h0 = (float)h0p[0];
  float rw = (float)WW / w0;
  float rh = (float)HH / h0;
  float s02 = 0.5f * (rw - 1.0f);
  float s12 = 0.5f * (rh - 1.0f);
  const float* K = K0 + b * 9;
  float k0 = rw * K[0] + s02 * K[6];
  float k1 = rw * K[1] + s02 * K[7];
  float k2 = rw * K[2] + s02 * K[8];
  float k3 = rh * K[3] + s12 * K[6];
  float k4 = rh * K[4] + s12 * K[7];
  float k5 = rh * K[5] + s12 * K[8];
  float k6 = K[6], k7 = K[7], k8 = K[8];
  double a = k0, bb = k1, c = k2, d = k3, e = k4, f = k5, g = k6, h = k7, i = k8;
  double cA = e * i - f * h;
  double cB = -(d * i - f * g);
  double cC = d * h - e * g;
  double det = a * cA + bb * cB + c * cC;
  double idet = 1.0 / det;
  float* o = cst + b * 12;
  o[0] = (float)(cA * idet);
  o[1] = (float)(-(bb * i - c * h) * idet);
  o[2] = (float)((bb * f - c * e) * idet);
  o[3] = (float)(cB * idet);
  o[4] = (float)((a * i - c * g) * idet);
  o[5] = (float)(-(a * f - c * d) * idet);
  o[6] = (float)(cC * idet);
  o[7] = (float)(-(a * h - bb * g) * idet);
  o[8] = (float)((a * e - bb * d) * idet);
  o[9] = k0 * baseline[b];
}

// ---------------------------------------------------------------------------
// Barrier-free fused kernel. One wave = one 60x8 output strip.
// Per row: xyz+products into a 5-deep register window (full unroll -> static),
// vertical 5-sums in registers (exact age order), horizontal 5-tap via a
// 64-column LDS exchange inside the wave (in-order DS, no __syncthreads).
// ---------------------------------------------------------------------------
__global__ __launch_bounds__(256, 4) void tmap_fused(
    const float* __restrict__ disp,
    const float* __restrict__ cst,
    float* __restrict__ out_depth,
    float* __restrict__ out_mask) {
  __shared__ float4 S0[4][64];   // vx, vy, vz, vxx   (per-wave slice)
  __shared__ float4 S1[4][64];   // vxy, vxz, vyy, vyz
  __shared__ float  S2[4][64];   // vzz

  const int lane = threadIdx.x;  // 0..63
  const int wv = threadIdx.y;    // 0..3
  const int unit = blockIdx.x * 4 + wv;
  const int b = unit / (NSX * NCY);
  const int rem = unit - b * (NSX * NCY);
  const int cy = rem / NSX;
  const int sx = rem - cy * NSX;
  const int gj0 = sx * OUTW;
  const int gi0 = cy * CH;

  const float* C = cst + b * 12;
  const float Ki01 = C[1], Ki11 = C[4], Ki21 = C[7];
  const float fxb = C[9];

  const int cj = gj0 + lane - 2;                 // this lane's staged column
  const bool colv = ((unsigned)cj < (unsigned)WW);
  const float jf = (float)cj;
  const float cx = fmaf(C[0], jf, C[2]);         // Ki00*j + Ki02
  const float cyk = fmaf(C[3], jf, C[5]);        // Ki10*j + Ki12
  const float czk = fmaf(C[6], jf, C[8]);        // Ki20*j + Ki22
  const float cwf = (float)(min(cj + 2, WW - 1) - max(cj - 2, 0) + 1);

  float4* const s0 = S0[wv];
  float4* const s1 = S1[wv];
  float* const s2 = S2[wv];

  int rdi[5];
#pragma unroll
  for (int w = 0; w < 5; ++w) rdi[w] = min(max(lane + w - 2, 0), 63);

  const float* const dispb = disp + (size_t)b * HH * WW;

  // 5-deep rolling window of xyz + products (static indices via full unroll)
  float bx[5], by[5], bz[5], bxx[5], bxy[5], bxz[5], byy[5], byz[5], bzz[5];

#define LOADROW(SLOT, T)                                              \
  {                                                                   \
    const int gi_ = gi0 - 2 + (T);                                    \
    float x_ = 0.f, y_ = 0.f, z_ = 0.f;                               \
    if (colv && gi_ >= 0 && gi_ < HH) {                               \
      const float dsp_ = dispb[gi_ * WW + cj];                        \
      const float depth_ =                                            \
          fxb * fast_rcp((float)WW * fmaxf(dsp_, 1e-6f));             \
      const float if_ = (float)gi_;                                   \
      x_ = depth_ * fmaf(Ki01, if_, cx);                              \
      y_ = depth_ * fmaf(Ki11, if_, cyk);                             \
      z_ = depth_ * fmaf(Ki21, if_, czk);                             \
    }                                                                 \
    bx[SLOT] = x_; by[SLOT] = y_; bz[SLOT] = z_;                      \
    bxx[SLOT] = x_ * x_; bxy[SLOT] = x_ * y_; bxz[SLOT] = x_ * z_;    \
    byy[SLOT] = y_ * y_; byz[SLOT] = y_ * z_; bzz[SLOT] = z_ * z_;    \
  }

  LOADROW(0, 0)
  LOADROW(1, 1)
  LOADROW(2, 2)
  LOADROW(3, 3)

#pragma unroll
  for (int orow = 0; orow < CH; ++orow) {
    // load bottom row of the window into the recycled slot (all static)
    LOADROW((orow + 4) % 5, orow + 4)
    // center row (for cond1 / depth output); z == depth (K row3 = [0,0,1])
    const float yc = by[(orow + 2) % 5];
    const float zc = bz[(orow + 2) % 5];

    // vertical 5-sums, exact top-to-bottom age order
    const int q0 = orow % 5, q1 = (orow + 1) % 5, q2 = (orow + 2) % 5,
              q3 = (orow + 3) % 5, q4 = (orow + 4) % 5;
    const float vx = (((bx[q0] + bx[q1]) + bx[q2]) + bx[q3]) + bx[q4];
    const float vy = (((by[q0] + by[q1]) + by[q2]) + by[q3]) + by[q4];
    const float vz = (((bz[q0] + bz[q1]) + bz[q2]) + bz[q3]) + bz[q4];
    const float vxx = (((bxx[q0] + bxx[q1]) + bxx[q2]) + bxx[q3]) + bxx[q4];
    const float vxy = (((bxy[q0] + bxy[q1]) + bxy[q2]) + bxy[q3]) + bxy[q4];
    const float vxz = (((bxz[q0] + bxz[q1]) + bxz[q2]) + bxz[q3]) + bxz[q4];
    const float vyy = (((byy[q0] + byy[q1]) + byy[q2]) + byy[q3]) + byy[q4];
    const float vyz = (((byz[q0] + byz[q1]) + byz[q2]) + byz[q3]) + byz[q4];
    const float vzz = (((bzz[q0] + bzz[q1]) + bzz[q2]) + bzz[q3]) + bzz[q4];

    // wave-internal column exchange (same-wave DS ops are in-order)
    s0[lane] = make_float4(vx, vy, vz, vxx);
    s1[lane] = make_float4(vxy, vxz, vyy, vyz);
    s2[lane] = vzz;
    __builtin_amdgcn_wave_barrier();

    float s1x = 0.f, s1y = 0.f, s1z = 0.f;
    float m00 = 0.f, m01 = 0.f, m02 = 0.f, m11 = 0.f, m12 = 0.f, m22 = 0.f;
#pragma unroll
    for (int w = 0; w < 5; ++w) {
      const float4 a4 = s0[rdi[w]];
      const float4 c4 = s1[rdi[w]];
      const float e1 = s2[rdi[w]];
      s1x += a4.x; s1y += a4.y; s1z += a4.z; m00 += a4.w;
      m01 += c4.x; m02 += c4.y; m11 += c4.z; m12 += c4.w;
      m22 += e1;
    }
    __builtin_amdgcn_wave_barrier();  // keep next iter's writes after reads

    const int gi = gi0 + orow;
    const float cnt =
        (float)(min(gi + 2, HH - 1) - max(gi - 2, 0) + 1) * cwf;
    const float rcnt = fast_rcp(cnt);

    const float Px = s1x * rcnt, Py = s1y * rcnt, Pz = s1z * rcnt;
    float a00 = m00 * rcnt - Px * Px;
    float a01 = m01 * rcnt - Px * Py;
    float a02 = m02 * rcnt - Px * Pz;
    float a11 = m11 * rcnt - Py * Py;
    float a12 = m12 * rcnt - Py * Pz;
    float a22 = m22 * rcnt - Pz * Pz;

    const float AmA = fmaxf(fmaxf(fabsf(a00), fabsf(a11)), fabsf(a22));
    const float AmB = fmaxf(fmaxf(fabsf(a01), fabsf(a02)), fabsf(a12));
    const float Amax = fmaxf(AmA, AmB);
    const float eval_zero = (Amax < 1e-6f) ? 1.0f : 0.0f;
    const float rAm = fast_rcp(fmaxf(Amax, 1e-6f));
    a00 *= rAm; a01 *= rAm; a02 *= rAm; a11 *= rAm; a12 *= rAm; a22 *= rAm;

    const float nrm = a01 * a01 + a02 * a02 + a12 * a12;
    const float q = (a00 + a11 + a22) * (1.0f / 3.0f);
    const float b00 = a00 - q, b11 = a11 - q, b22 = a22 - q;
    const float p = fast_sqrt(
        (b00 * b00 + b11 * b11 + b22 * b22 + 2.0f * nrm) * (1.0f / 6.0f));
    const float eig_triple = ((p < 1e-6f) ? 1.0f : 0.0f) * (1.0f - eval_zero);
    const float c00 = b11 * b22 - a12 * a12;
    const float c01 = a01 * b22 - a12 * a02;
    const float c02 = a01 * a12 - b11 * a02;
    const float rpm = fast_rcp(fmaxf(p, 1e-6f));
    const float det = (b00 * c00 - a01 * c01 + a02 * c02) * (rpm * rpm * rpm);
    const float half_det = fminf(fmaxf(0.5f * det, -1.0f), 1.0f);
    const float t = fast_acos(half_det);
    const float rev = t * 0.05305164769729845f;  // 1/(6*pi)
    const float beta2 = 2.0f * cos_rev(rev);
    const float beta0 = 2.0f * cos_rev(rev + (1.0f / 3.0f));
    const float wsel = (1.0f - eval_zero) * (1.0f - eig_triple);
    const float e0 = eig_triple * q + wsel * fmaf(p, beta0, q);
    const float dd2 = (2.0f * beta0 + beta2) * (beta0 - beta2);
    const float denom = wsel * p * fast_sqrt(fmaxf(dd2, 0.0f));
    const float evec_zero = (denom < 1e-6f) ? 1.0f : 0.0f;
    const float ny_num = fast_sqrt(
        fmaxf(e0 * e0 - (a00 + a22) * e0 + (a00 * a22 - a02 * a02), 0.0f));
    const float ny =
        fminf(fmaxf(ny_num * fast_rcp(fmaxf(denom, 1e-6f)), 0.0f), 1.0f);
    const float plane_xz = (1.0f - evec_zero) * ny;

    if (lane >= 2 && lane < 2 + OUTW && cj < WW) {
      const int idx = (b * HH + gi) * WW + cj;
      out_depth[idx] = zc;
      const float cond1 = (yc > 0.3f) ? 1.0f : 0.0f;
      const float cond2 = (plane_xz > 0.85f) ? 1.0f : 0.0f;
      out_mask[idx] = cond1 * cond2;
    }
  }
#undef LOADROW
}

extern "C" void kernel_launch(void* const* d_in, const int* in_sizes, int n_in,
                              void* d_out, int out_size, void* d_ws, size_t ws_size,
                              hipStream_t stream) {
  const float* disp = (const float*)d_in[0];
  const float* K0 = (const float*)d_in[1];
  const float* baseline = (const float*)d_in[2];
  const int* h0 = (const int*)d_in[3];
  const int* w0 = (const int*)d_in[4];

  float* cst = (float*)d_ws;  // 8 * 12 floats = 384 B
  float* out_depth = (float*)d_out;
  float* out_mask = out_depth + (size_t)BATCH * HH * WW;

  prep_kernel<<<1, BATCH, 0, stream>>>(K0, baseline, h0, w0, cst);

  const int nblocks = (NSX * NCY * BATCH) / 4;  // 2112
  tmap_fused<<<nblocks, dim3(64, 4), 0, stream>>>(disp, cst, out_depth, out_mask);
}